// Round 1
// baseline (890.715 us; speedup 1.0000x reference)
//
#include <hip/hip_runtime.h>
#include <math.h>

#define IN_CH 256
#define HID 64
#define HEADS 8
#define F1 512   // HEADS*HID
#define OUT_CH 16
#define NEG 0.2f

// ---------------- CSR build ----------------

__global__ void init_counts(int* counts, int* cursor, int n) {
  int i = blockIdx.x * blockDim.x + threadIdx.x;
  if (i < n) { counts[i] = 0; cursor[i] = 0; }
}

__global__ void count_kernel(const int* __restrict__ ei, int E, int N, int* counts) {
  int e = blockIdx.x * blockDim.x + threadIdx.x;
  int ET = E + N;
  if (e >= ET) return;
  int dst = (e < E) ? ei[E + e] : (e - E);
  atomicAdd(&counts[dst], 1);
}

__global__ void scan_kernel(const int* __restrict__ counts, int* __restrict__ offsets, int n) {
  __shared__ int lds[1024];
  __shared__ int carry;
  if (threadIdx.x == 0) carry = 0;
  __syncthreads();
  for (int base = 0; base < n; base += 1024) {
    int i = base + (int)threadIdx.x;
    int v = (i < n) ? counts[i] : 0;
    lds[threadIdx.x] = v;
    __syncthreads();
    for (int off = 1; off < 1024; off <<= 1) {
      int t = (threadIdx.x >= (unsigned)off) ? lds[threadIdx.x - off] : 0;
      __syncthreads();
      lds[threadIdx.x] += t;
      __syncthreads();
    }
    int incl = lds[threadIdx.x];
    int tot = lds[1023];
    if (i < n) offsets[i] = carry + incl - v;
    __syncthreads();
    if (threadIdx.x == 0) carry += tot;
    __syncthreads();
  }
  if (threadIdx.x == 0) offsets[n] = carry;
}

__global__ void fill_kernel(const int* __restrict__ ei, int E, int N,
                            const int* __restrict__ offsets, int* cursor,
                            int* __restrict__ csr_src) {
  int e = blockIdx.x * blockDim.x + threadIdx.x;
  int ET = E + N;
  if (e >= ET) return;
  int src, dst;
  if (e < E) { src = ei[e]; dst = ei[E + e]; }
  else       { src = e - E; dst = e - E; }
  int pos = atomicAdd(&cursor[dst], 1);
  csr_src[offsets[dst] + pos] = src;
}

// ---------------- GEMM1: h1 = x @ W1  (M x 256) @ (256 x 512) ----------------

__global__ __launch_bounds__(256) void gemm1_kernel(const float* __restrict__ A,
                                                    const float* __restrict__ B,
                                                    float* __restrict__ C, int M) {
  __shared__ float sA[16][65];  // [k][m]
  __shared__ float sB[16][65];  // [k][n]
  int bm = blockIdx.y * 64;
  int bn = blockIdx.x * 64;
  int tid = threadIdx.x;
  int tm = (tid >> 4) * 4;
  int tn = (tid & 15) * 4;
  float acc[4][4] = {};
  for (int k0 = 0; k0 < IN_CH; k0 += 16) {
    #pragma unroll
    for (int i = tid; i < 64 * 16; i += 256) {
      int r = i >> 4, cc = i & 15;
      int gr = bm + r;
      sA[cc][r] = (gr < M) ? A[(size_t)gr * IN_CH + k0 + cc] : 0.f;
    }
    #pragma unroll
    for (int i = tid; i < 16 * 64; i += 256) {
      int r = i >> 6, cc = i & 63;
      sB[r][cc] = B[(size_t)(k0 + r) * F1 + bn + cc];
    }
    __syncthreads();
    #pragma unroll
    for (int kk = 0; kk < 16; ++kk) {
      float a[4], b[4];
      #pragma unroll
      for (int j = 0; j < 4; ++j) a[j] = sA[kk][tm + j];
      #pragma unroll
      for (int j = 0; j < 4; ++j) b[j] = sB[kk][tn + j];
      #pragma unroll
      for (int xx = 0; xx < 4; ++xx)
        #pragma unroll
        for (int yy = 0; yy < 4; ++yy) acc[xx][yy] += a[xx] * b[yy];
    }
    __syncthreads();
  }
  #pragma unroll
  for (int xx = 0; xx < 4; ++xx) {
    int gr = bm + tm + xx;
    if (gr < M) {
      #pragma unroll
      for (int yy = 0; yy < 4; ++yy)
        C[(size_t)gr * F1 + bn + tn + yy] = acc[xx][yy];
    }
  }
}

// ---------------- alpha1: per-node per-head dot with a_src/a_dst ----------------

__global__ void alpha1_kernel(const float* __restrict__ h1, const float* __restrict__ a_src,
                              const float* __restrict__ a_dst, float* __restrict__ as1,
                              float* __restrict__ ad1, int N) {
  int n = blockIdx.x;
  int tid = threadIdx.x;  // 512
  float v = h1[(size_t)n * F1 + tid];
  float s = v * a_src[tid];
  float d = v * a_dst[tid];
  #pragma unroll
  for (int off = 32; off; off >>= 1) { s += __shfl_xor(s, off); d += __shfl_xor(d, off); }
  int lane = tid & 63;
  int h = tid >> 6;
  if (lane == 0) { as1[n * HEADS + h] = s; ad1[n * HEADS + h] = d; }
}

// ---------------- aggr1: segment softmax + weighted gather + bias + ELU ----------------

#define CHUNK 32
__global__ __launch_bounds__(512) void aggr1_kernel(const float* __restrict__ h1,
                                                    const float* __restrict__ as1,
                                                    const float* __restrict__ ad1,
                                                    const int* __restrict__ offsets,
                                                    const int* __restrict__ csr_src,
                                                    const float* __restrict__ b1,
                                                    float* __restrict__ out1, int N) {
  int node = blockIdx.x;
  int tid = threadIdx.x;  // 512
  int h = tid >> 6;
  int beg = offsets[node];
  int deg = offsets[node + 1] - beg;
  __shared__ float s_max[HEADS];
  __shared__ float s_den[HEADS];
  __shared__ float s_red[512];
  __shared__ float s_p[CHUNK][HEADS];
  __shared__ int s_src[CHUNK];
  // pass 1: per-head max of leaky(as[src]+ad[dst])
  {
    int hh = tid & 7;
    float adv = ad1[node * HEADS + hh];
    float m = -INFINITY;
    for (int i = tid >> 3; i < deg; i += 64) {
      int s = csr_src[beg + i];
      float e = as1[s * HEADS + hh] + adv;
      e = (e > 0.f) ? e : NEG * e;
      m = fmaxf(m, e);
    }
    s_red[tid] = m;
    __syncthreads();
    for (int off = 256; off >= 8; off >>= 1) {
      if (tid < off) s_red[tid] = fmaxf(s_red[tid], s_red[tid + off]);
      __syncthreads();
    }
    if (tid < 8) { s_max[tid] = s_red[tid]; s_den[tid] = 0.f; }
    __syncthreads();
  }
  // pass 2: chunked p-compute + gather-accumulate
  float acc = 0.f;
  for (int cbase = 0; cbase < deg; cbase += CHUNK) {
    int cnt = min(CHUNK, deg - cbase);
    if (tid < cnt) s_src[tid] = csr_src[beg + cbase + tid];
    __syncthreads();
    if (tid < cnt * HEADS) {
      int j = tid >> 3, hh = tid & 7;
      int s = s_src[j];
      float e = as1[s * HEADS + hh] + ad1[node * HEADS + hh];
      e = (e > 0.f) ? e : NEG * e;
      float p = expf(e - s_max[hh]);
      s_p[j][hh] = p;
      atomicAdd(&s_den[hh], p);
    }
    __syncthreads();
    for (int j = 0; j < cnt; ++j) {
      acc += s_p[j][h] * h1[(size_t)s_src[j] * F1 + tid];
    }
    __syncthreads();
  }
  float den = s_den[h];
  float val = acc / (den + 1e-16f) + b1[tid];
  val = (val > 0.f) ? val : expm1f(val);  // ELU
  out1[(size_t)node * F1 + tid] = val;
}

// ---------------- GEMM2 + alpha2: t2 = elu_out @ W2 (512 x 16) ----------------

__global__ __launch_bounds__(256) void gemm2_kernel(const float* __restrict__ hin,
                                                    const float* __restrict__ W2,
                                                    const float* __restrict__ a_src2,
                                                    const float* __restrict__ a_dst2,
                                                    float* __restrict__ t2,
                                                    float* __restrict__ as2,
                                                    float* __restrict__ ad2, int N) {
  __shared__ float sW[F1 * OUT_CH];  // 32 KB
  int tid = threadIdx.x;  // 256
  for (int i = tid; i < F1 * OUT_CH; i += 256) sW[i] = W2[i];
  __syncthreads();
  int nl = tid >> 4;
  int c = tid & 15;
  int n = blockIdx.x * 16 + nl;
  if (n >= N) return;
  float acc = 0.f;
  const float* hrow = hin + (size_t)n * F1;
  for (int k = 0; k < F1; ++k) acc += hrow[k] * sW[k * OUT_CH + c];
  t2[n * OUT_CH + c] = acc;
  float s = acc * a_src2[c];
  float d = acc * a_dst2[c];
  #pragma unroll
  for (int off = 1; off < 16; off <<= 1) { s += __shfl_xor(s, off); d += __shfl_xor(d, off); }
  if (c == 0) { as2[n] = s; ad2[n] = d; }
}

// ---------------- aggr2: segment softmax + gather + log_softmax ----------------

__global__ __launch_bounds__(64) void aggr2_kernel(const float* __restrict__ t2,
                                                   const float* __restrict__ as2,
                                                   const float* __restrict__ ad2,
                                                   const int* __restrict__ offsets,
                                                   const int* __restrict__ csr_src,
                                                   const float* __restrict__ b2,
                                                   float* __restrict__ out, int N) {
  int node = blockIdx.x;
  int lane = threadIdx.x;  // 64
  int beg = offsets[node];
  int deg = offsets[node + 1] - beg;
  float ad = ad2[node];
  float m = -INFINITY;
  for (int i = lane; i < deg; i += 64) {
    float e = as2[csr_src[beg + i]] + ad;
    e = (e > 0.f) ? e : NEG * e;
    m = fmaxf(m, e);
  }
  #pragma unroll
  for (int off = 32; off; off >>= 1) m = fmaxf(m, __shfl_xor(m, off));
  float acc = 0.f, den = 0.f;
  int eg = lane >> 4, c = lane & 15;
  for (int base = 0; base < deg; base += 4) {
    int j = base + eg;
    if (j < deg) {
      int s = csr_src[beg + j];
      float e = as2[s] + ad;
      e = (e > 0.f) ? e : NEG * e;
      float p = expf(e - m);
      acc += p * t2[s * OUT_CH + c];
      if (c == 0) den += p;
    }
  }
  acc += __shfl_xor(acc, 16); acc += __shfl_xor(acc, 32);
  den += __shfl_xor(den, 16); den += __shfl_xor(den, 32);
  den = __shfl(den, 0);
  float val = acc / (den + 1e-16f) + b2[c];
  // log_softmax over 16 channels (xor within 16-lane group)
  float mx = val;
  #pragma unroll
  for (int off = 1; off < 16; off <<= 1) mx = fmaxf(mx, __shfl_xor(mx, off));
  float ex = expf(val - mx);
  float se = ex;
  #pragma unroll
  for (int off = 1; off < 16; off <<= 1) se += __shfl_xor(se, off);
  float ls = val - mx - logf(se);
  if (lane < 16) out[node * OUT_CH + lane] = ls;
}

// ---------------- launch ----------------

extern "C" void kernel_launch(void* const* d_in, const int* in_sizes, int n_in,
                              void* d_out, int out_size, void* d_ws, size_t ws_size,
                              hipStream_t stream) {
  const float* x      = (const float*)d_in[0];
  const int*   ei     = (const int*)d_in[1];
  const float* W1     = (const float*)d_in[2];
  const float* a_src1 = (const float*)d_in[3];
  const float* a_dst1 = (const float*)d_in[4];
  const float* b1     = (const float*)d_in[5];
  const float* W2     = (const float*)d_in[6];
  const float* a_src2 = (const float*)d_in[7];
  const float* a_dst2 = (const float*)d_in[8];
  const float* b2     = (const float*)d_in[9];
  float* out = (float*)d_out;

  int N = in_sizes[0] / IN_CH;
  int E = in_sizes[1] / 2;
  int ET = E + N;

  char* w = (char*)d_ws;
  auto alloc = [&](size_t bytes) -> void* {
    void* p = (void*)w;
    w += (bytes + 255) & ~(size_t)255;
    return p;
  };
  float* h1    = (float*)alloc((size_t)N * F1 * 4);
  float* out1  = (float*)alloc((size_t)N * F1 * 4);
  float* as1   = (float*)alloc((size_t)N * HEADS * 4);
  float* ad1   = (float*)alloc((size_t)N * HEADS * 4);
  float* t2    = (float*)alloc((size_t)N * OUT_CH * 4);
  float* as2   = (float*)alloc((size_t)N * 4);
  float* ad2   = (float*)alloc((size_t)N * 4);
  int* counts  = (int*)alloc((size_t)N * 4);
  int* offsets = (int*)alloc((size_t)(N + 1) * 4);
  int* cursor  = (int*)alloc((size_t)N * 4);
  int* csr_src = (int*)alloc((size_t)ET * 4);

  init_counts<<<(N + 255) / 256, 256, 0, stream>>>(counts, cursor, N);
  count_kernel<<<(ET + 255) / 256, 256, 0, stream>>>(ei, E, N, counts);
  scan_kernel<<<1, 1024, 0, stream>>>(counts, offsets, N);
  fill_kernel<<<(ET + 255) / 256, 256, 0, stream>>>(ei, E, N, offsets, cursor, csr_src);

  dim3 g1(F1 / 64, (N + 63) / 64);
  gemm1_kernel<<<g1, 256, 0, stream>>>(x, W1, h1, N);
  alpha1_kernel<<<N, 512, 0, stream>>>(h1, a_src1, a_dst1, as1, ad1, N);
  aggr1_kernel<<<N, 512, 0, stream>>>(h1, as1, ad1, offsets, csr_src, b1, out1, N);
  gemm2_kernel<<<(N + 15) / 16, 256, 0, stream>>>(out1, W2, a_src2, a_dst2, t2, as2, ad2, N);
  aggr2_kernel<<<N, 64, 0, stream>>>(t2, as2, ad2, offsets, csr_src, b2, out, N);
}

// Round 2
// 373.568 us; speedup vs baseline: 2.3843x; 2.3843x over previous
//
#include <hip/hip_runtime.h>
#include <math.h>

#define IN_CH 256
#define HID 64
#define HEADS 8
#define F1 512   // HEADS*HID
#define OUT_CH 16
#define NEG 0.2f

typedef __attribute__((ext_vector_type(8))) short bf16x8;
typedef __attribute__((ext_vector_type(4))) float f32x4;

__device__ __forceinline__ float bflo(unsigned int v) {
  unsigned int t = v << 16; return __builtin_bit_cast(float, t);
}
__device__ __forceinline__ float bfhi(unsigned int v) {
  unsigned int t = v & 0xFFFF0000u; return __builtin_bit_cast(float, t);
}
__device__ __forceinline__ unsigned short f2bf(float f) {
  unsigned int u = __builtin_bit_cast(unsigned int, f);
  u += 0x7FFFu + ((u >> 16) & 1u);
  return (unsigned short)(u >> 16);
}
__device__ __forceinline__ void gld_lds16(const void* g, void* l) {
  __builtin_amdgcn_global_load_lds(
      (const __attribute__((address_space(1))) unsigned int*)g,
      (__attribute__((address_space(3))) unsigned int*)l, 16, 0, 0);
}

// ---------------- CSR build ----------------

__global__ void init_counts(int* counts, int* cursor, int n) {
  int i = blockIdx.x * blockDim.x + threadIdx.x;
  if (i < n) { counts[i] = 0; cursor[i] = 0; }
}

__global__ void count_kernel(const int* __restrict__ ei, int E, int N, int* counts) {
  int e = blockIdx.x * blockDim.x + threadIdx.x;
  int ET = E + N;
  if (e >= ET) return;
  int dst = (e < E) ? ei[E + e] : (e - E);
  atomicAdd(&counts[dst], 1);
}

__global__ __launch_bounds__(1024) void scan1_kernel(const int* __restrict__ counts,
                                                     int* __restrict__ offsets,
                                                     int* __restrict__ bsum, int n) {
  __shared__ int lds[1024];
  int t = threadIdx.x;
  int i = blockIdx.x * 1024 + t;
  int v = (i < n) ? counts[i] : 0;
  lds[t] = v;
  __syncthreads();
  for (int off = 1; off < 1024; off <<= 1) {
    int u = (t >= off) ? lds[t - off] : 0;
    __syncthreads();
    lds[t] += u;
    __syncthreads();
  }
  if (i < n) offsets[i] = lds[t] - v;  // block-local exclusive
  if (t == 1023) bsum[blockIdx.x] = lds[1023];
}

__global__ void scan2_kernel(const int* __restrict__ bsum, int* __restrict__ bpre,
                             int nb, int* __restrict__ offsets, int n) {
  if (threadIdx.x == 0 && blockIdx.x == 0) {
    int run = 0;
    for (int b = 0; b < nb; ++b) { bpre[b] = run; run += bsum[b]; }
    offsets[n] = run;
  }
}

__global__ __launch_bounds__(1024) void scan3_kernel(int* __restrict__ offsets,
                                                     const int* __restrict__ bpre, int n) {
  int i = blockIdx.x * 1024 + threadIdx.x;
  if (i < n) offsets[i] += bpre[blockIdx.x];
}

__global__ void fill_kernel(const int* __restrict__ ei, int E, int N,
                            const int* __restrict__ offsets, int* cursor,
                            int* __restrict__ csr_src) {
  int e = blockIdx.x * blockDim.x + threadIdx.x;
  int ET = E + N;
  if (e >= ET) return;
  int src, dst;
  if (e < E) { src = ei[e]; dst = ei[E + e]; }
  else       { src = e - E; dst = e - E; }
  int pos = atomicAdd(&cursor[dst], 1);
  csr_src[offsets[dst] + pos] = src;
}

// ---------------- dtype converts ----------------

__global__ void convert_f32_bf16(const float* __restrict__ in, unsigned short* __restrict__ outp,
                                 size_t n) {
  size_t i = ((size_t)blockIdx.x * blockDim.x + threadIdx.x) * 4;
  size_t stride = (size_t)gridDim.x * blockDim.x * 4;
  for (; i + 3 < n; i += stride) {
    float4 v = *(const float4*)(in + i);
    ushort4 o;
    o.x = f2bf(v.x); o.y = f2bf(v.y); o.z = f2bf(v.z); o.w = f2bf(v.w);
    *(ushort4*)(outp + i) = o;
  }
}

// W1 [256][512] -> W1T bf16 [512][256]
__global__ void convert_w1t(const float* __restrict__ W1, unsigned short* __restrict__ W1T) {
  int i = blockIdx.x * blockDim.x + threadIdx.x;  // over 512*256
  if (i >= F1 * IN_CH) return;
  int n = i >> 8, k = i & 255;
  W1T[i] = f2bf(W1[k * F1 + n]);
}

// W2 [512][16] -> W2T bf16 [16][512]
__global__ void convert_w2t(const float* __restrict__ W2, unsigned short* __restrict__ W2T) {
  int i = blockIdx.x * blockDim.x + threadIdx.x;  // over 16*512
  if (i >= OUT_CH * F1) return;
  int n = i >> 9, k = i & 511;
  W2T[i] = f2bf(W2[k * OUT_CH + n]);
}

// ---------------- GEMM1: h1 = x @ W1 (bf16 MFMA, B^T form) ----------------
// A: x_bf16 [M][256] row-major. B: W1T [512][256] ([n][k]). C: h1 bf16 [M][512].

__global__ __launch_bounds__(256) void gemm1_mfma(const unsigned short* __restrict__ A,
                                                  const unsigned short* __restrict__ B,
                                                  unsigned short* __restrict__ C, int M) {
  __shared__ __align__(16) short sA[128 * 32];
  __shared__ __align__(16) short sB[128 * 32];
  int bid = blockIdx.x;
  int bm = (bid >> 2) * 128;
  int bn = (bid & 3) * 128;
  int tid = threadIdx.x;
  int w = tid >> 6, l = tid & 63;
  int wm = (w >> 1) * 64, wn = (w & 1) * 64;
  f32x4 acc[4][4];
  #pragma unroll
  for (int i = 0; i < 4; ++i)
    #pragma unroll
    for (int j = 0; j < 4; ++j) acc[i][j] = (f32x4){0.f, 0.f, 0.f, 0.f};
  int lr = l >> 2;        // row within 16-row group per issue
  int lc = (l & 3) * 8;   // k-element offset (8 bf16 = 16B)
  for (int k0 = 0; k0 < IN_CH; k0 += 32) {
    #pragma unroll
    for (int i = 0; i < 2; ++i) {
      int ra = bm + i * 64 + w * 16 + lr;
      if (ra >= M) ra = M - 1;
      gld_lds16(A + (size_t)ra * IN_CH + k0 + lc, (char*)sA + i * 4096 + w * 1024);
      int rb = bn + i * 64 + w * 16 + lr;
      gld_lds16(B + (size_t)rb * IN_CH + k0 + lc, (char*)sB + i * 4096 + w * 1024);
    }
    __syncthreads();
    bf16x8 af[4], bfv[4];
    #pragma unroll
    for (int mi = 0; mi < 4; ++mi)
      af[mi] = *(const bf16x8*)&sA[(wm + mi * 16 + (l & 15)) * 32 + (l >> 4) * 8];
    #pragma unroll
    for (int nj = 0; nj < 4; ++nj)
      bfv[nj] = *(const bf16x8*)&sB[(wn + nj * 16 + (l & 15)) * 32 + (l >> 4) * 8];
    #pragma unroll
    for (int mi = 0; mi < 4; ++mi)
      #pragma unroll
      for (int nj = 0; nj < 4; ++nj)
        acc[mi][nj] = __builtin_amdgcn_mfma_f32_16x16x32_bf16(af[mi], bfv[nj], acc[mi][nj], 0, 0, 0);
    __syncthreads();
  }
  #pragma unroll
  for (int mi = 0; mi < 4; ++mi) {
    #pragma unroll
    for (int j = 0; j < 4; ++j) {
      int r = bm + wm + mi * 16 + (l >> 4) * 4 + j;
      if (r < M) {
        #pragma unroll
        for (int nj = 0; nj < 4; ++nj) {
          int c = bn + wn + nj * 16 + (l & 15);
          C[(size_t)r * F1 + c] = f2bf(acc[mi][nj][j]);
        }
      }
    }
  }
}

// ---------------- alpha1: per-node per-head dots (bf16 h1) ----------------

__global__ __launch_bounds__(256) void alpha1_kernel(const unsigned int* __restrict__ h1u,
                                                     const float* __restrict__ a_src,
                                                     const float* __restrict__ a_dst,
                                                     float* __restrict__ as1,
                                                     float* __restrict__ ad1, int N) {
  int n = blockIdx.x, tid = threadIdx.x;  // 256 thr, 2 ch each
  unsigned int v = h1u[(size_t)n * 256 + tid];
  float lo = bflo(v), hi = bfhi(v);
  float s = lo * a_src[2 * tid] + hi * a_src[2 * tid + 1];
  float d = lo * a_dst[2 * tid] + hi * a_dst[2 * tid + 1];
  #pragma unroll
  for (int off = 16; off; off >>= 1) { s += __shfl_xor(s, off); d += __shfl_xor(d, off); }
  if ((tid & 31) == 0) { int h = tid >> 5; as1[n * HEADS + h] = s; ad1[n * HEADS + h] = d; }
}

// ---------------- aggr1: segment softmax + bf16 gather + bias + ELU ----------------

__global__ __launch_bounds__(256) void aggr1_kernel(const unsigned int* __restrict__ h1u,
                                                    const float* __restrict__ as1,
                                                    const float* __restrict__ ad1,
                                                    const int* __restrict__ offsets,
                                                    const int* __restrict__ csr_src,
                                                    const float* __restrict__ b1,
                                                    unsigned int* __restrict__ out1u, int N) {
  int node = blockIdx.x, tid = threadIdx.x;  // 256 thr, 2 ch each
  int hh = tid & 7, slot = tid >> 3;  // p-compute role
  int h = tid >> 5;                   // gather role (head of channels 2tid,2tid+1)
  int beg = offsets[node], deg = offsets[node + 1] - beg;
  __shared__ float s_red[256];
  __shared__ float s_max[8];
  __shared__ float s_den[8];
  __shared__ float s_p[32][8];
  __shared__ int s_src[32];
  float adv = ad1[node * 8 + hh];
  // pass 1: per-head max
  float m = -1e30f;
  for (int i = slot; i < deg; i += 32) {
    int s = csr_src[beg + i];
    float e = as1[s * 8 + hh] + adv;
    e = (e > 0.f) ? e : NEG * e;
    m = fmaxf(m, e);
  }
  s_red[slot * 8 + hh] = m;
  __syncthreads();
  for (int off = 16; off >= 1; off >>= 1) {
    if (slot < off) s_red[slot * 8 + hh] = fmaxf(s_red[slot * 8 + hh], s_red[(slot + off) * 8 + hh]);
    __syncthreads();
  }
  if (tid < 8) s_max[tid] = s_red[tid];
  __syncthreads();
  float mh = s_max[hh];
  float pden = 0.f, acc0 = 0.f, acc1 = 0.f;
  for (int cb = 0; cb < deg; cb += 32) {
    int cnt = min(32, deg - cb);
    if (tid < cnt) s_src[tid] = csr_src[beg + cb + tid];
    __syncthreads();
    if (slot < cnt) {
      int s = s_src[slot];
      float e = as1[s * 8 + hh] + adv;
      e = (e > 0.f) ? e : NEG * e;
      float p = __expf(e - mh);
      s_p[slot][hh] = p;
      pden += p;
    }
    __syncthreads();
    for (int j = 0; j < cnt; ++j) {
      unsigned int v = h1u[(size_t)s_src[j] * 256 + tid];
      float p = s_p[j][h];
      acc0 += p * bflo(v);
      acc1 += p * bfhi(v);
    }
    __syncthreads();
  }
  s_red[slot * 8 + hh] = pden;
  __syncthreads();
  for (int off = 16; off >= 1; off >>= 1) {
    if (slot < off) s_red[slot * 8 + hh] += s_red[(slot + off) * 8 + hh];
    __syncthreads();
  }
  if (tid < 8) s_den[tid] = s_red[tid];
  __syncthreads();
  float den = s_den[h] + 1e-16f;
  float v0 = acc0 / den + b1[2 * tid];
  float v1 = acc1 / den + b1[2 * tid + 1];
  v0 = (v0 > 0.f) ? v0 : expm1f(v0);
  v1 = (v1 > 0.f) ? v1 : expm1f(v1);
  out1u[(size_t)node * 256 + tid] = (unsigned int)f2bf(v0) | ((unsigned int)f2bf(v1) << 16);
}

// ---------------- GEMM2 (MFMA) + fused alpha2 ----------------
// A: out1 bf16 [M][512]. B: W2T bf16 [16][512]. t2 fp32 [M][16].

__global__ __launch_bounds__(256) void gemm2_mfma(const unsigned short* __restrict__ A,
                                                  const unsigned short* __restrict__ W2T,
                                                  const float* __restrict__ a_src2,
                                                  const float* __restrict__ a_dst2,
                                                  float* __restrict__ t2,
                                                  float* __restrict__ as2,
                                                  float* __restrict__ ad2, int M) {
  __shared__ __align__(16) short sA[256 * 32];   // 16 KB
  __shared__ __align__(16) short sW[16 * 512];   // 16 KB
  int tid = threadIdx.x, w = tid >> 6, l = tid & 63;
  for (int i = tid; i < 1024; i += 256) ((uint4*)sW)[i] = ((const uint4*)W2T)[i];
  int bm = blockIdx.x * 256;
  f32x4 acc[4];
  #pragma unroll
  for (int mi = 0; mi < 4; ++mi) acc[mi] = (f32x4){0.f, 0.f, 0.f, 0.f};
  int lr = l >> 2, lc = (l & 3) * 8;
  for (int k0 = 0; k0 < F1; k0 += 32) {
    #pragma unroll
    for (int i = 0; i < 4; ++i) {
      int ra = bm + i * 64 + w * 16 + lr;
      if (ra >= M) ra = M - 1;
      gld_lds16(A + (size_t)ra * F1 + k0 + lc, (char*)sA + i * 4096 + w * 1024);
    }
    __syncthreads();
    bf16x8 bfv = *(const bf16x8*)&sW[(l & 15) * 512 + k0 + (l >> 4) * 8];
    #pragma unroll
    for (int mi = 0; mi < 4; ++mi) {
      bf16x8 af = *(const bf16x8*)&sA[(w * 64 + mi * 16 + (l & 15)) * 32 + (l >> 4) * 8];
      acc[mi] = __builtin_amdgcn_mfma_f32_16x16x32_bf16(af, bfv, acc[mi], 0, 0, 0);
    }
    __syncthreads();
  }
  float asv = a_src2[l & 15], adv = a_dst2[l & 15];
  #pragma unroll
  for (int mi = 0; mi < 4; ++mi) {
    #pragma unroll
    for (int j = 0; j < 4; ++j) {
      int r = bm + w * 64 + mi * 16 + (l >> 4) * 4 + j;
      float val = acc[mi][j];
      float s = val * asv, d = val * adv;
      s += __shfl_xor(s, 1); s += __shfl_xor(s, 2); s += __shfl_xor(s, 4); s += __shfl_xor(s, 8);
      d += __shfl_xor(d, 1); d += __shfl_xor(d, 2); d += __shfl_xor(d, 4); d += __shfl_xor(d, 8);
      if (r < M) {
        t2[(size_t)r * OUT_CH + (l & 15)] = val;
        if ((l & 15) == 0) { as2[r] = s; ad2[r] = d; }
      }
    }
  }
}

// ---------------- aggr2: segment softmax + gather + log_softmax ----------------

__global__ __launch_bounds__(64) void aggr2_kernel(const float* __restrict__ t2,
                                                   const float* __restrict__ as2,
                                                   const float* __restrict__ ad2,
                                                   const int* __restrict__ offsets,
                                                   const int* __restrict__ csr_src,
                                                   const float* __restrict__ b2,
                                                   float* __restrict__ out, int N) {
  int node = blockIdx.x;
  int lane = threadIdx.x;  // 64
  int beg = offsets[node];
  int deg = offsets[node + 1] - beg;
  float ad = ad2[node];
  float m = -1e30f;
  for (int i = lane; i < deg; i += 64) {
    float e = as2[csr_src[beg + i]] + ad;
    e = (e > 0.f) ? e : NEG * e;
    m = fmaxf(m, e);
  }
  #pragma unroll
  for (int off = 32; off; off >>= 1) m = fmaxf(m, __shfl_xor(m, off));
  float acc = 0.f, den = 0.f;
  int eg = lane >> 4, c = lane & 15;
  for (int base = 0; base < deg; base += 4) {
    int j = base + eg;
    if (j < deg) {
      int s = csr_src[beg + j];
      float e = as2[s] + ad;
      e = (e > 0.f) ? e : NEG * e;
      float p = __expf(e - m);
      acc += p * t2[(size_t)s * OUT_CH + c];
      if (c == 0) den += p;
    }
  }
  acc += __shfl_xor(acc, 16); acc += __shfl_xor(acc, 32);
  den += __shfl_xor(den, 16); den += __shfl_xor(den, 32);
  den = __shfl(den, 0);
  float val = acc / (den + 1e-16f) + b2[c];
  float mx = val;
  #pragma unroll
  for (int off = 1; off < 16; off <<= 1) mx = fmaxf(mx, __shfl_xor(mx, off));
  float ex = __expf(val - mx);
  float se = ex;
  #pragma unroll
  for (int off = 1; off < 16; off <<= 1) se += __shfl_xor(se, off);
  float ls = val - mx - logf(se);
  if (lane < 16) out[(size_t)node * OUT_CH + lane] = ls;
}

// ---------------- launch ----------------

extern "C" void kernel_launch(void* const* d_in, const int* in_sizes, int n_in,
                              void* d_out, int out_size, void* d_ws, size_t ws_size,
                              hipStream_t stream) {
  const float* x      = (const float*)d_in[0];
  const int*   ei     = (const int*)d_in[1];
  const float* W1     = (const float*)d_in[2];
  const float* a_src1 = (const float*)d_in[3];
  const float* a_dst1 = (const float*)d_in[4];
  const float* b1     = (const float*)d_in[5];
  const float* W2     = (const float*)d_in[6];
  const float* a_src2 = (const float*)d_in[7];
  const float* a_dst2 = (const float*)d_in[8];
  const float* b2     = (const float*)d_in[9];
  float* out = (float*)d_out;

  int N = in_sizes[0] / IN_CH;
  int E = in_sizes[1] / 2;
  int ET = E + N;

  char* w = (char*)d_ws;
  auto alloc = [&](size_t bytes) -> void* {
    void* p = (void*)w;
    w += (bytes + 255) & ~(size_t)255;
    return p;
  };
  unsigned short* h1b   = (unsigned short*)alloc((size_t)N * F1 * 2);
  unsigned short* out1b = (unsigned short*)alloc((size_t)N * F1 * 2);
  unsigned short* xb    = (unsigned short*)alloc((size_t)N * IN_CH * 2);
  unsigned short* w1t   = (unsigned short*)alloc((size_t)F1 * IN_CH * 2);
  unsigned short* w2t   = (unsigned short*)alloc((size_t)OUT_CH * F1 * 2);
  float* as1   = (float*)alloc((size_t)N * HEADS * 4);
  float* ad1   = (float*)alloc((size_t)N * HEADS * 4);
  float* t2    = (float*)alloc((size_t)N * OUT_CH * 4);
  float* as2   = (float*)alloc((size_t)N * 4);
  float* ad2   = (float*)alloc((size_t)N * 4);
  int* counts  = (int*)alloc((size_t)N * 4);
  int* offsets = (int*)alloc((size_t)(N + 1) * 4);
  int* cursor  = (int*)alloc((size_t)N * 4);
  int* bsum    = (int*)alloc(256 * 4);
  int* bpre    = (int*)alloc(256 * 4);
  int* csr_src = (int*)alloc((size_t)ET * 4);

  int nb = (N + 1023) / 1024;

  init_counts<<<(N + 255) / 256, 256, 0, stream>>>(counts, cursor, N);
  count_kernel<<<(ET + 255) / 256, 256, 0, stream>>>(ei, E, N, counts);
  scan1_kernel<<<nb, 1024, 0, stream>>>(counts, offsets, bsum, N);
  scan2_kernel<<<1, 64, 0, stream>>>(bsum, bpre, nb, offsets, N);
  scan3_kernel<<<nb, 1024, 0, stream>>>(offsets, bpre, N);
  fill_kernel<<<(ET + 255) / 256, 256, 0, stream>>>(ei, E, N, offsets, cursor, csr_src);

  convert_f32_bf16<<<2048, 256, 0, stream>>>(x, xb, (size_t)N * IN_CH);
  convert_w1t<<<(F1 * IN_CH + 255) / 256, 256, 0, stream>>>(W1, w1t);
  convert_w2t<<<(OUT_CH * F1 + 255) / 256, 256, 0, stream>>>(W2, w2t);

  int gx = ((N + 127) / 128) * 4;
  gemm1_mfma<<<gx, 256, 0, stream>>>(xb, w1t, h1b, N);
  alpha1_kernel<<<N, 256, 0, stream>>>((const unsigned int*)h1b, a_src1, a_dst1, as1, ad1, N);
  aggr1_kernel<<<N, 256, 0, stream>>>((const unsigned int*)h1b, as1, ad1, offsets, csr_src,
                                      b1, (unsigned int*)out1b, N);
  gemm2_mfma<<<(N + 255) / 256, 256, 0, stream>>>(out1b, w2t, a_src2, a_dst2, t2, as2, ad2, N);
  aggr2_kernel<<<N, 64, 0, stream>>>(t2, as2, ad2, offsets, csr_src, b2, out, N);
}

// Round 3
// 351.992 us; speedup vs baseline: 2.5305x; 1.0613x over previous
//
#include <hip/hip_runtime.h>
#include <math.h>

#define IN_CH 256
#define HID 64
#define HEADS 8
#define F1 512   // HEADS*HID
#define OUT_CH 16
#define NEG 0.2f

typedef __attribute__((ext_vector_type(8))) short bf16x8;
typedef __attribute__((ext_vector_type(4))) float f32x4;

__device__ __forceinline__ float bflo(unsigned int v) {
  unsigned int t = v << 16; return __builtin_bit_cast(float, t);
}
__device__ __forceinline__ float bfhi(unsigned int v) {
  unsigned int t = v & 0xFFFF0000u; return __builtin_bit_cast(float, t);
}
__device__ __forceinline__ unsigned short f2bf(float f) {
  unsigned int u = __builtin_bit_cast(unsigned int, f);
  u += 0x7FFFu + ((u >> 16) & 1u);
  return (unsigned short)(u >> 16);
}
__device__ __forceinline__ void gld_lds16(const void* g, void* l) {
  __builtin_amdgcn_global_load_lds(
      (const __attribute__((address_space(1))) unsigned int*)g,
      (__attribute__((address_space(3))) unsigned int*)l, 16, 0, 0);
}

// ---------------- CSR build ----------------

__global__ void init_kernel(int* counts, int* cursor, float* as1, float* ad1, int n) {
  int i = blockIdx.x * blockDim.x + threadIdx.x;
  if (i < n) { counts[i] = 0; cursor[i] = 0; }
  if (i < n * HEADS) { as1[i] = 0.f; ad1[i] = 0.f; }
}

__global__ void count_kernel(const int* __restrict__ ei, int E, int N, int* counts) {
  int e = blockIdx.x * blockDim.x + threadIdx.x;
  int ET = E + N;
  if (e >= ET) return;
  int dst = (e < E) ? ei[E + e] : (e - E);
  atomicAdd(&counts[dst], 1);
}

__global__ __launch_bounds__(1024) void scan1_kernel(const int* __restrict__ counts,
                                                     int* __restrict__ offsets,
                                                     int* __restrict__ bsum, int n) {
  __shared__ int lds[1024];
  int t = threadIdx.x;
  int i = blockIdx.x * 1024 + t;
  int v = (i < n) ? counts[i] : 0;
  lds[t] = v;
  __syncthreads();
  for (int off = 1; off < 1024; off <<= 1) {
    int u = (t >= off) ? lds[t - off] : 0;
    __syncthreads();
    lds[t] += u;
    __syncthreads();
  }
  if (i < n) offsets[i] = lds[t] - v;  // block-local exclusive
  if (t == 1023) bsum[blockIdx.x] = lds[1023];
}

__global__ void scan2_kernel(const int* __restrict__ bsum, int* __restrict__ bpre,
                             int nb, int* __restrict__ offsets, int n) {
  if (threadIdx.x == 0 && blockIdx.x == 0) {
    int run = 0;
    for (int b = 0; b < nb; ++b) { bpre[b] = run; run += bsum[b]; }
    offsets[n] = run;
  }
}

__global__ __launch_bounds__(1024) void scan3_kernel(int* __restrict__ offsets,
                                                     const int* __restrict__ bpre, int n) {
  int i = blockIdx.x * 1024 + threadIdx.x;
  if (i < n) offsets[i] += bpre[blockIdx.x];
}

__global__ void fill_kernel(const int* __restrict__ ei, int E, int N,
                            const int* __restrict__ offsets, int* cursor,
                            int* __restrict__ csr_src) {
  int e = blockIdx.x * blockDim.x + threadIdx.x;
  int ET = E + N;
  if (e >= ET) return;
  int src, dst;
  if (e < E) { src = ei[e]; dst = ei[E + e]; }
  else       { src = e - E; dst = e - E; }
  int pos = atomicAdd(&cursor[dst], 1);
  csr_src[offsets[dst] + pos] = src;
}

// ---------------- dtype converts ----------------

__global__ void convert_f32_bf16(const float* __restrict__ in, unsigned short* __restrict__ outp,
                                 size_t n) {
  size_t i = ((size_t)blockIdx.x * blockDim.x + threadIdx.x) * 4;
  size_t stride = (size_t)gridDim.x * blockDim.x * 4;
  for (; i + 3 < n; i += stride) {
    float4 v = *(const float4*)(in + i);
    ushort4 o;
    o.x = f2bf(v.x); o.y = f2bf(v.y); o.z = f2bf(v.z); o.w = f2bf(v.w);
    *(ushort4*)(outp + i) = o;
  }
}

// W1 [256][512] -> W1T bf16 [512][256]
__global__ void convert_w1t(const float* __restrict__ W1, unsigned short* __restrict__ W1T) {
  int i = blockIdx.x * blockDim.x + threadIdx.x;
  if (i >= F1 * IN_CH) return;
  int n = i >> 8, k = i & 255;
  W1T[i] = f2bf(W1[k * F1 + n]);
}

// W2 [512][16] -> W2T bf16 [16][512]
__global__ void convert_w2t(const float* __restrict__ W2, unsigned short* __restrict__ W2T) {
  int i = blockIdx.x * blockDim.x + threadIdx.x;
  if (i >= OUT_CH * F1) return;
  int n = i >> 9, k = i & 511;
  W2T[i] = f2bf(W2[k * OUT_CH + n]);
}

// ---------------- GEMM1: h1 = x @ W1 (bf16 MFMA) + fused alpha1 ----------------
// A: x_bf16 [M][256]. B: W1T [512][256]. C: h1 bf16 [M][512]. as1/ad1 via atomics.

__global__ __launch_bounds__(256) void gemm1_mfma(const unsigned short* __restrict__ A,
                                                  const unsigned short* __restrict__ B,
                                                  const float* __restrict__ Asrc,
                                                  const float* __restrict__ Adst,
                                                  unsigned short* __restrict__ C,
                                                  float* __restrict__ as1,
                                                  float* __restrict__ ad1, int M) {
  __shared__ __align__(16) short sA[128 * 32];
  __shared__ __align__(16) short sB[128 * 32];
  int bid = blockIdx.x;
  int bm = (bid >> 2) * 128;
  int bn = (bid & 3) * 128;
  int tid = threadIdx.x;
  int w = tid >> 6, l = tid & 63;
  int wm = (w >> 1) * 64, wn = (w & 1) * 64;
  f32x4 acc[4][4];
  #pragma unroll
  for (int i = 0; i < 4; ++i)
    #pragma unroll
    for (int j = 0; j < 4; ++j) acc[i][j] = (f32x4){0.f, 0.f, 0.f, 0.f};
  int lr = l >> 2;
  int lc = (l & 3) * 8;
  for (int k0 = 0; k0 < IN_CH; k0 += 32) {
    #pragma unroll
    for (int i = 0; i < 2; ++i) {
      int ra = bm + i * 64 + w * 16 + lr;
      if (ra >= M) ra = M - 1;
      gld_lds16(A + (size_t)ra * IN_CH + k0 + lc, (char*)sA + i * 4096 + w * 1024);
      int rb = bn + i * 64 + w * 16 + lr;
      gld_lds16(B + (size_t)rb * IN_CH + k0 + lc, (char*)sB + i * 4096 + w * 1024);
    }
    __syncthreads();
    bf16x8 af[4], bfv[4];
    #pragma unroll
    for (int mi = 0; mi < 4; ++mi)
      af[mi] = *(const bf16x8*)&sA[(wm + mi * 16 + (l & 15)) * 32 + (l >> 4) * 8];
    #pragma unroll
    for (int nj = 0; nj < 4; ++nj)
      bfv[nj] = *(const bf16x8*)&sB[(wn + nj * 16 + (l & 15)) * 32 + (l >> 4) * 8];
    #pragma unroll
    for (int mi = 0; mi < 4; ++mi)
      #pragma unroll
      for (int nj = 0; nj < 4; ++nj)
        acc[mi][nj] = __builtin_amdgcn_mfma_f32_16x16x32_bf16(af[mi], bfv[nj], acc[mi][nj], 0, 0, 0);
    __syncthreads();
  }
  // C store
  #pragma unroll
  for (int mi = 0; mi < 4; ++mi) {
    #pragma unroll
    for (int j = 0; j < 4; ++j) {
      int r = bm + wm + mi * 16 + (l >> 4) * 4 + j;
      if (r < M) {
        #pragma unroll
        for (int nj = 0; nj < 4; ++nj) {
          int c = bn + wn + nj * 16 + (l & 15);
          C[(size_t)r * F1 + c] = f2bf(acc[mi][nj][j]);
        }
      }
    }
  }
  // fused alpha1: per-row dots with a_src1/a_dst1 over this block's 64-col slice (one head)
  int head = (bn + wn) >> 6;
  float asv[4], adv[4];
  #pragma unroll
  for (int nj = 0; nj < 4; ++nj) {
    int c = bn + wn + nj * 16 + (l & 15);
    asv[nj] = Asrc[c]; adv[nj] = Adst[c];
  }
  #pragma unroll
  for (int mi = 0; mi < 4; ++mi) {
    #pragma unroll
    for (int j = 0; j < 4; ++j) {
      int r = bm + wm + mi * 16 + (l >> 4) * 4 + j;
      float sv = 0.f, dv = 0.f;
      #pragma unroll
      for (int nj = 0; nj < 4; ++nj) {
        float v = acc[mi][nj][j];
        sv += v * asv[nj]; dv += v * adv[nj];
      }
      sv += __shfl_xor(sv, 1); sv += __shfl_xor(sv, 2);
      sv += __shfl_xor(sv, 4); sv += __shfl_xor(sv, 8);
      dv += __shfl_xor(dv, 1); dv += __shfl_xor(dv, 2);
      dv += __shfl_xor(dv, 4); dv += __shfl_xor(dv, 8);
      if (r < M && (l & 15) == 0) {
        atomicAdd(&as1[r * HEADS + head], sv);
        atomicAdd(&ad1[r * HEADS + head], dv);
      }
    }
  }
}

// ---------------- aggr1: segment softmax (no max pass) + 16B gather + bias + ELU ----------------

__global__ __launch_bounds__(256) void aggr1_kernel(const uint4* __restrict__ h1v,
                                                    const float* __restrict__ as1,
                                                    const float* __restrict__ ad1,
                                                    const int* __restrict__ offsets,
                                                    const int* __restrict__ csr_src,
                                                    const float* __restrict__ b1,
                                                    unsigned int* __restrict__ out1u, int N) {
  int node = blockIdx.x, tid = threadIdx.x;
  int w = tid >> 6, l = tid & 63;
  int hh = tid & 7, slot = tid >> 3;
  int beg = offsets[node], deg = offsets[node + 1] - beg;
  __shared__ int s_src[32];
  __shared__ float s_p[32][8];
  __shared__ float s_red[256];
  __shared__ float s_accR[4][512];
  float adv = ad1[node * HEADS + hh];
  float pden = 0.f;
  float acc[8] = {};
  for (int cb = 0; cb < deg; cb += 32) {
    int cnt = min(32, deg - cb);
    if (slot < cnt) {
      int s = csr_src[beg + cb + slot];
      float e = as1[s * HEADS + hh] + adv;
      e = (e > 0.f) ? e : NEG * e;
      float p = __expf(e);
      s_p[slot][hh] = p;
      pden += p;
      if (hh == 0) s_src[slot] = s;
    }
    __syncthreads();
    for (int j = w; j < cnt; j += 4) {
      uint4 v = h1v[(size_t)s_src[j] * 64 + l];
      float p = s_p[j][l >> 3];
      acc[0] += p * bflo(v.x); acc[1] += p * bfhi(v.x);
      acc[2] += p * bflo(v.y); acc[3] += p * bfhi(v.y);
      acc[4] += p * bflo(v.z); acc[5] += p * bfhi(v.z);
      acc[6] += p * bflo(v.w); acc[7] += p * bfhi(v.w);
    }
    __syncthreads();
  }
  // denom reduce over slots (tid = slot*8 + hh)
  s_red[tid] = pden;
  __syncthreads();
  for (int off = 128; off >= 8; off >>= 1) {
    if (tid < off) s_red[tid] += s_red[tid + off];
    __syncthreads();
  }
  // cross-wave acc combine
  *(float4*)&s_accR[w][l * 8]     = make_float4(acc[0], acc[1], acc[2], acc[3]);
  *(float4*)&s_accR[w][l * 8 + 4] = make_float4(acc[4], acc[5], acc[6], acc[7]);
  __syncthreads();
  int c0 = 2 * tid, c1 = c0 + 1;
  float den = s_red[c0 >> 6] + 1e-16f;
  float v0 = (s_accR[0][c0] + s_accR[1][c0] + s_accR[2][c0] + s_accR[3][c0]) / den + b1[c0];
  float v1 = (s_accR[0][c1] + s_accR[1][c1] + s_accR[2][c1] + s_accR[3][c1]) / den + b1[c1];
  v0 = (v0 > 0.f) ? v0 : expm1f(v0);
  v1 = (v1 > 0.f) ? v1 : expm1f(v1);
  out1u[(size_t)node * 256 + tid] = (unsigned int)f2bf(v0) | ((unsigned int)f2bf(v1) << 16);
}

// ---------------- GEMM2 (MFMA) + fused alpha2 ----------------
// A: out1 bf16 [M][512]. B: W2T bf16 [16][512]. t2 fp32 [M][16].

__global__ __launch_bounds__(256) void gemm2_mfma(const unsigned short* __restrict__ A,
                                                  const unsigned short* __restrict__ W2T,
                                                  const float* __restrict__ a_src2,
                                                  const float* __restrict__ a_dst2,
                                                  float* __restrict__ t2,
                                                  float* __restrict__ as2,
                                                  float* __restrict__ ad2, int M) {
  __shared__ __align__(16) short sA[128 * 32];   // 8 KB
  __shared__ __align__(16) short sW[16 * 512];   // 16 KB
  int tid = threadIdx.x, w = tid >> 6, l = tid & 63;
  for (int i = tid; i < 1024; i += 256) ((uint4*)sW)[i] = ((const uint4*)W2T)[i];
  int bm = blockIdx.x * 128;
  f32x4 acc[2];
  acc[0] = (f32x4){0.f, 0.f, 0.f, 0.f};
  acc[1] = (f32x4){0.f, 0.f, 0.f, 0.f};
  int lr = l >> 2, lc = (l & 3) * 8;
  for (int k0 = 0; k0 < F1; k0 += 32) {
    #pragma unroll
    for (int i = 0; i < 2; ++i) {
      int ra = bm + i * 64 + w * 16 + lr;
      if (ra >= M) ra = M - 1;
      gld_lds16(A + (size_t)ra * F1 + k0 + lc, (char*)sA + i * 4096 + w * 1024);
    }
    __syncthreads();
    bf16x8 bfv = *(const bf16x8*)&sW[(l & 15) * 512 + k0 + (l >> 4) * 8];
    #pragma unroll
    for (int mi = 0; mi < 2; ++mi) {
      bf16x8 af = *(const bf16x8*)&sA[(w * 32 + mi * 16 + (l & 15)) * 32 + (l >> 4) * 8];
      acc[mi] = __builtin_amdgcn_mfma_f32_16x16x32_bf16(af, bfv, acc[mi], 0, 0, 0);
    }
    __syncthreads();
  }
  float asv = a_src2[l & 15], adv = a_dst2[l & 15];
  #pragma unroll
  for (int mi = 0; mi < 2; ++mi) {
    #pragma unroll
    for (int j = 0; j < 4; ++j) {
      int r = bm + w * 32 + mi * 16 + (l >> 4) * 4 + j;
      float val = acc[mi][j];
      float s = val * asv, d = val * adv;
      s += __shfl_xor(s, 1); s += __shfl_xor(s, 2); s += __shfl_xor(s, 4); s += __shfl_xor(s, 8);
      d += __shfl_xor(d, 1); d += __shfl_xor(d, 2); d += __shfl_xor(d, 4); d += __shfl_xor(d, 8);
      if (r < M) {
        t2[(size_t)r * OUT_CH + (l & 15)] = val;
        if ((l & 15) == 0) { as2[r] = s; ad2[r] = d; }
      }
    }
  }
}

// ---------------- aggr2: segment softmax (no max) + gather + log_softmax ----------------

__global__ __launch_bounds__(64) void aggr2_kernel(const float* __restrict__ t2,
                                                   const float* __restrict__ as2,
                                                   const float* __restrict__ ad2,
                                                   const int* __restrict__ offsets,
                                                   const int* __restrict__ csr_src,
                                                   const float* __restrict__ b2,
                                                   float* __restrict__ out, int N) {
  int node = blockIdx.x;
  int lane = threadIdx.x;  // 64
  int beg = offsets[node];
  int deg = offsets[node + 1] - beg;
  float ad = ad2[node];
  float acc = 0.f, den = 0.f;
  int eg = lane >> 4, c = lane & 15;
  for (int base = 0; base < deg; base += 4) {
    int j = base + eg;
    if (j < deg) {
      int s = csr_src[beg + j];
      float e = as2[s] + ad;
      e = (e > 0.f) ? e : NEG * e;
      float p = __expf(e);
      acc += p * t2[(size_t)s * OUT_CH + c];
      if (c == 0) den += p;
    }
  }
  acc += __shfl_xor(acc, 16); acc += __shfl_xor(acc, 32);
  den += __shfl_xor(den, 16); den += __shfl_xor(den, 32);
  den = __shfl(den, 0);
  float val = acc / (den + 1e-16f) + b2[c];
  float mx = val;
  #pragma unroll
  for (int off = 1; off < 16; off <<= 1) mx = fmaxf(mx, __shfl_xor(mx, off));
  float ex = __expf(val - mx);
  float se = ex;
  #pragma unroll
  for (int off = 1; off < 16; off <<= 1) se += __shfl_xor(se, off);
  float ls = val - mx - logf(se);
  if (lane < 16) out[(size_t)node * OUT_CH + lane] = ls;
}

// ---------------- launch ----------------

extern "C" void kernel_launch(void* const* d_in, const int* in_sizes, int n_in,
                              void* d_out, int out_size, void* d_ws, size_t ws_size,
                              hipStream_t stream) {
  const float* x      = (const float*)d_in[0];
  const int*   ei     = (const int*)d_in[1];
  const float* W1     = (const float*)d_in[2];
  const float* a_src1 = (const float*)d_in[3];
  const float* a_dst1 = (const float*)d_in[4];
  const float* b1     = (const float*)d_in[5];
  const float* W2     = (const float*)d_in[6];
  const float* a_src2 = (const float*)d_in[7];
  const float* a_dst2 = (const float*)d_in[8];
  const float* b2     = (const float*)d_in[9];
  float* out = (float*)d_out;

  int N = in_sizes[0] / IN_CH;
  int E = in_sizes[1] / 2;
  int ET = E + N;

  char* w = (char*)d_ws;
  auto alloc = [&](size_t bytes) -> void* {
    void* p = (void*)w;
    w += (bytes + 255) & ~(size_t)255;
    return p;
  };
  unsigned short* h1b   = (unsigned short*)alloc((size_t)N * F1 * 2);
  unsigned short* out1b = (unsigned short*)alloc((size_t)N * F1 * 2);
  unsigned short* xb    = (unsigned short*)alloc((size_t)N * IN_CH * 2);
  unsigned short* w1t   = (unsigned short*)alloc((size_t)F1 * IN_CH * 2);
  unsigned short* w2t   = (unsigned short*)alloc((size_t)OUT_CH * F1 * 2);
  float* as1   = (float*)alloc((size_t)N * HEADS * 4);
  float* ad1   = (float*)alloc((size_t)N * HEADS * 4);
  float* t2    = (float*)alloc((size_t)N * OUT_CH * 4);
  float* as2   = (float*)alloc((size_t)N * 4);
  float* ad2   = (float*)alloc((size_t)N * 4);
  int* counts  = (int*)alloc((size_t)N * 4);
  int* offsets = (int*)alloc((size_t)(N + 1) * 4);
  int* cursor  = (int*)alloc((size_t)N * 4);
  int* bsum    = (int*)alloc(256 * 4);
  int* bpre    = (int*)alloc(256 * 4);
  int* csr_src = (int*)alloc((size_t)ET * 4);

  int nb = (N + 1023) / 1024;

  init_kernel<<<(N * HEADS + 255) / 256, 256, 0, stream>>>(counts, cursor, as1, ad1, N);
  count_kernel<<<(ET + 255) / 256, 256, 0, stream>>>(ei, E, N, counts);
  scan1_kernel<<<nb, 1024, 0, stream>>>(counts, offsets, bsum, N);
  scan2_kernel<<<1, 64, 0, stream>>>(bsum, bpre, nb, offsets, N);
  scan3_kernel<<<nb, 1024, 0, stream>>>(offsets, bpre, N);
  fill_kernel<<<(ET + 255) / 256, 256, 0, stream>>>(ei, E, N, offsets, cursor, csr_src);

  convert_f32_bf16<<<2048, 256, 0, stream>>>(x, xb, (size_t)N * IN_CH);
  convert_w1t<<<(F1 * IN_CH + 255) / 256, 256, 0, stream>>>(W1, w1t);
  convert_w2t<<<(OUT_CH * F1 + 255) / 256, 256, 0, stream>>>(W2, w2t);

  int gx = ((N + 127) / 128) * 4;
  gemm1_mfma<<<gx, 256, 0, stream>>>(xb, w1t, a_src1, a_dst1, h1b, as1, ad1, N);
  aggr1_kernel<<<N, 256, 0, stream>>>((const uint4*)h1b, as1, ad1, offsets, csr_src,
                                      b1, (unsigned int*)out1b, N);
  gemm2_mfma<<<(N + 127) / 128, 256, 0, stream>>>(out1b, w2t, a_src2, a_dst2, t2, as2, ad2, N);
  aggr2_kernel<<<N, 64, 0, stream>>>(t2, as2, ad2, offsets, csr_src, b2, out, N);
}

// Round 4
// 338.354 us; speedup vs baseline: 2.6325x; 1.0403x over previous
//
#include <hip/hip_runtime.h>
#include <math.h>

#define IN_CH 256
#define HID 64
#define HEADS 8
#define F1 512   // HEADS*HID
#define OUT_CH 16
#define NEG 0.2f

typedef __attribute__((ext_vector_type(8))) short bf16x8;
typedef __attribute__((ext_vector_type(4))) float f32x4;

__device__ __forceinline__ float bflo(unsigned int v) {
  unsigned int t = v << 16; return __builtin_bit_cast(float, t);
}
__device__ __forceinline__ float bfhi(unsigned int v) {
  unsigned int t = v & 0xFFFF0000u; return __builtin_bit_cast(float, t);
}
__device__ __forceinline__ unsigned short f2bf(float f) {
  unsigned int u = __builtin_bit_cast(unsigned int, f);
  u += 0x7FFFu + ((u >> 16) & 1u);
  return (unsigned short)(u >> 16);
}
__device__ __forceinline__ void gld_lds16(const void* g, void* l) {
  __builtin_amdgcn_global_load_lds(
      (const __attribute__((address_space(1))) unsigned int*)g,
      (__attribute__((address_space(3))) unsigned int*)l, 16, 0, 0);
}

// ---------------- CSR build + prep ----------------

__global__ void init_kernel(int* counts, int* cursor, float* as1, float* ad1, int n) {
  int i = blockIdx.x * blockDim.x + threadIdx.x;
  if (i < n) { counts[i] = 0; cursor[i] = 0; }
  if (i < n * HEADS) { as1[i] = 0.f; ad1[i] = 0.f; }
}

// count + convert x / W1T / W2T, all independent
__global__ void prep_kernel(const int* __restrict__ ei, int E, int N, int* counts,
                            const float* __restrict__ x, unsigned short* __restrict__ xb,
                            const float* __restrict__ W1, unsigned short* __restrict__ W1T,
                            const float* __restrict__ W2, unsigned short* __restrict__ W2T) {
  int idx = blockIdx.x * blockDim.x + threadIdx.x;
  int ET = E + N;
  if (idx < ET) {
    int dst = (idx < E) ? ei[E + idx] : (idx - E);
    atomicAdd(&counts[dst], 1);
  }
  size_t nx = (size_t)N * IN_CH;
  size_t stride = (size_t)gridDim.x * blockDim.x * 4;
  for (size_t i = (size_t)idx * 4; i + 3 < nx; i += stride) {
    float4 v = *(const float4*)(x + i);
    ushort4 o;
    o.x = f2bf(v.x); o.y = f2bf(v.y); o.z = f2bf(v.z); o.w = f2bf(v.w);
    *(ushort4*)(xb + i) = o;
  }
  if (idx < F1 * IN_CH) {
    int n = idx >> 8, k = idx & 255;
    W1T[idx] = f2bf(W1[k * F1 + n]);
  }
  if (idx < OUT_CH * F1) {
    int n = idx >> 9, k = idx & 511;
    W2T[idx] = f2bf(W2[k * OUT_CH + n]);
  }
}

__global__ __launch_bounds__(1024) void scan1_kernel(const int* __restrict__ counts,
                                                     int* __restrict__ offsets,
                                                     int* __restrict__ bsum, int n) {
  __shared__ int lds[1024];
  int t = threadIdx.x;
  int i = blockIdx.x * 1024 + t;
  int v = (i < n) ? counts[i] : 0;
  lds[t] = v;
  __syncthreads();
  for (int off = 1; off < 1024; off <<= 1) {
    int u = (t >= off) ? lds[t - off] : 0;
    __syncthreads();
    lds[t] += u;
    __syncthreads();
  }
  if (i < n) offsets[i] = lds[t] - v;  // block-local exclusive
  if (t == 1023) bsum[blockIdx.x] = lds[1023];
}

__global__ void scan2_kernel(const int* __restrict__ bsum, int* __restrict__ bpre,
                             int nb, int* __restrict__ offsets, int n) {
  if (threadIdx.x == 0 && blockIdx.x == 0) {
    int run = 0;
    for (int b = 0; b < nb; ++b) { bpre[b] = run; run += bsum[b]; }
    offsets[n] = run;
  }
}

__global__ __launch_bounds__(1024) void scan3_kernel(int* __restrict__ offsets,
                                                     const int* __restrict__ bpre, int n) {
  int i = blockIdx.x * 1024 + threadIdx.x;
  if (i < n) offsets[i] += bpre[blockIdx.x];
}

__global__ void fill_kernel(const int* __restrict__ ei, int E, int N,
                            const int* __restrict__ offsets, int* cursor,
                            int* __restrict__ csr_src) {
  int e = blockIdx.x * blockDim.x + threadIdx.x;
  int ET = E + N;
  if (e >= ET) return;
  int src, dst;
  if (e < E) { src = ei[e]; dst = ei[E + e]; }
  else       { src = e - E; dst = e - E; }
  int pos = atomicAdd(&cursor[dst], 1);
  csr_src[offsets[dst] + pos] = src;
}

// ---------------- GEMM1: h1 = x @ W1 (bf16 MFMA) + fused alpha1 ----------------

__global__ __launch_bounds__(256) void gemm1_mfma(const unsigned short* __restrict__ A,
                                                  const unsigned short* __restrict__ B,
                                                  const float* __restrict__ Asrc,
                                                  const float* __restrict__ Adst,
                                                  unsigned short* __restrict__ C,
                                                  float* __restrict__ as1,
                                                  float* __restrict__ ad1, int M) {
  __shared__ __align__(16) short sA[128 * 32];
  __shared__ __align__(16) short sB[128 * 32];
  int bid = blockIdx.x;
  int bm = (bid >> 2) * 128;
  int bn = (bid & 3) * 128;
  int tid = threadIdx.x;
  int w = tid >> 6, l = tid & 63;
  int wm = (w >> 1) * 64, wn = (w & 1) * 64;
  f32x4 acc[4][4];
  #pragma unroll
  for (int i = 0; i < 4; ++i)
    #pragma unroll
    for (int j = 0; j < 4; ++j) acc[i][j] = (f32x4){0.f, 0.f, 0.f, 0.f};
  int lr = l >> 2;
  int lc = (l & 3) * 8;
  for (int k0 = 0; k0 < IN_CH; k0 += 32) {
    #pragma unroll
    for (int i = 0; i < 2; ++i) {
      int ra = bm + i * 64 + w * 16 + lr;
      if (ra >= M) ra = M - 1;
      gld_lds16(A + (size_t)ra * IN_CH + k0 + lc, (char*)sA + i * 4096 + w * 1024);
      int rb = bn + i * 64 + w * 16 + lr;
      gld_lds16(B + (size_t)rb * IN_CH + k0 + lc, (char*)sB + i * 4096 + w * 1024);
    }
    __syncthreads();
    bf16x8 af[4], bfv[4];
    #pragma unroll
    for (int mi = 0; mi < 4; ++mi)
      af[mi] = *(const bf16x8*)&sA[(wm + mi * 16 + (l & 15)) * 32 + (l >> 4) * 8];
    #pragma unroll
    for (int nj = 0; nj < 4; ++nj)
      bfv[nj] = *(const bf16x8*)&sB[(wn + nj * 16 + (l & 15)) * 32 + (l >> 4) * 8];
    #pragma unroll
    for (int mi = 0; mi < 4; ++mi)
      #pragma unroll
      for (int nj = 0; nj < 4; ++nj)
        acc[mi][nj] = __builtin_amdgcn_mfma_f32_16x16x32_bf16(af[mi], bfv[nj], acc[mi][nj], 0, 0, 0);
    __syncthreads();
  }
  // C store
  #pragma unroll
  for (int mi = 0; mi < 4; ++mi) {
    #pragma unroll
    for (int j = 0; j < 4; ++j) {
      int r = bm + wm + mi * 16 + (l >> 4) * 4 + j;
      if (r < M) {
        #pragma unroll
        for (int nj = 0; nj < 4; ++nj) {
          int c = bn + wn + nj * 16 + (l & 15);
          C[(size_t)r * F1 + c] = f2bf(acc[mi][nj][j]);
        }
      }
    }
  }
  // fused alpha1
  int head = (bn + wn) >> 6;
  float asv[4], adv[4];
  #pragma unroll
  for (int nj = 0; nj < 4; ++nj) {
    int c = bn + wn + nj * 16 + (l & 15);
    asv[nj] = Asrc[c]; adv[nj] = Adst[c];
  }
  #pragma unroll
  for (int mi = 0; mi < 4; ++mi) {
    #pragma unroll
    for (int j = 0; j < 4; ++j) {
      int r = bm + wm + mi * 16 + (l >> 4) * 4 + j;
      float sv = 0.f, dv = 0.f;
      #pragma unroll
      for (int nj = 0; nj < 4; ++nj) {
        float v = acc[mi][nj][j];
        sv += v * asv[nj]; dv += v * adv[nj];
      }
      sv += __shfl_xor(sv, 1); sv += __shfl_xor(sv, 2);
      sv += __shfl_xor(sv, 4); sv += __shfl_xor(sv, 8);
      dv += __shfl_xor(dv, 1); dv += __shfl_xor(dv, 2);
      dv += __shfl_xor(dv, 4); dv += __shfl_xor(dv, 8);
      if (r < M && (l & 15) == 0) {
        atomicAdd(&as1[r * HEADS + head], sv);
        atomicAdd(&ad1[r * HEADS + head], dv);
      }
    }
  }
}

// ---------------- aggr1: one wave per node, no barriers/LDS ----------------
// Wave reads full 1KB h1 row per uint4 issue; p via shfl; denom via shfl_xor.

__global__ __launch_bounds__(256) void aggr1_kernel(const uint4* __restrict__ h1v,
                                                    const float* __restrict__ as1,
                                                    const float* __restrict__ ad1,
                                                    const int* __restrict__ offsets,
                                                    const int* __restrict__ csr_src,
                                                    const float* __restrict__ b1,
                                                    uint4* __restrict__ out1v, int N) {
  int tid = threadIdx.x;
  int w = tid >> 6, l = tid & 63;
  int node = blockIdx.x * 4 + w;
  if (node >= N) return;
  int beg = offsets[node], deg = offsets[node + 1] - beg;
  int he = l & 7;            // head role in p-compute (lane = e*8 + h)
  int hc = l >> 3;           // head of my channels (ch = l*8 .. l*8+7)
  float adv = ad1[node * HEADS + he];
  float pden = 0.f;
  float acc[8] = {};
  for (int c0 = 0; c0 < deg; c0 += 8) {
    int cnt = min(8, deg - c0);
    int e = l >> 3;
    int s8 = 0;
    float p8 = 0.f;
    if (e < cnt) {
      s8 = csr_src[beg + c0 + e];
      float ev = as1[s8 * HEADS + he] + adv;
      ev = (ev > 0.f) ? ev : NEG * ev;
      p8 = __expf(ev);
      pden += p8;
    }
    for (int j = 0; j < cnt; ++j) {
      int s = __shfl(s8, j * 8);
      float p = __shfl(p8, j * 8 + hc);
      uint4 v = h1v[(size_t)s * 64 + l];
      acc[0] += p * bflo(v.x); acc[1] += p * bfhi(v.x);
      acc[2] += p * bflo(v.y); acc[3] += p * bfhi(v.y);
      acc[4] += p * bflo(v.z); acc[5] += p * bfhi(v.z);
      acc[6] += p * bflo(v.w); acc[7] += p * bfhi(v.w);
    }
  }
  // denom reduce: lanes sharing (l&7) sum -> every lane holds den[l&7]
  pden += __shfl_xor(pden, 8);
  pden += __shfl_xor(pden, 16);
  pden += __shfl_xor(pden, 32);
  float den = __shfl(pden, hc) + 1e-16f;
  float4 bv0 = *(const float4*)&b1[l * 8];
  float4 bv1 = *(const float4*)&b1[l * 8 + 4];
  float o[8];
  o[0] = acc[0] / den + bv0.x; o[1] = acc[1] / den + bv0.y;
  o[2] = acc[2] / den + bv0.z; o[3] = acc[3] / den + bv0.w;
  o[4] = acc[4] / den + bv1.x; o[5] = acc[5] / den + bv1.y;
  o[6] = acc[6] / den + bv1.z; o[7] = acc[7] / den + bv1.w;
  #pragma unroll
  for (int i = 0; i < 8; ++i) o[i] = (o[i] > 0.f) ? o[i] : expm1f(o[i]);
  uint4 ov;
  ov.x = (unsigned int)f2bf(o[0]) | ((unsigned int)f2bf(o[1]) << 16);
  ov.y = (unsigned int)f2bf(o[2]) | ((unsigned int)f2bf(o[3]) << 16);
  ov.z = (unsigned int)f2bf(o[4]) | ((unsigned int)f2bf(o[5]) << 16);
  ov.w = (unsigned int)f2bf(o[6]) | ((unsigned int)f2bf(o[7]) << 16);
  out1v[(size_t)node * 64 + l] = ov;
}

// ---------------- GEMM2 (MFMA) + fused alpha2 ----------------

__global__ __launch_bounds__(256) void gemm2_mfma(const unsigned short* __restrict__ A,
                                                  const unsigned short* __restrict__ W2T,
                                                  const float* __restrict__ a_src2,
                                                  const float* __restrict__ a_dst2,
                                                  float* __restrict__ t2,
                                                  float* __restrict__ as2,
                                                  float* __restrict__ ad2, int M) {
  __shared__ __align__(16) short sA[128 * 32];   // 8 KB
  __shared__ __align__(16) short sW[16 * 512];   // 16 KB
  int tid = threadIdx.x, w = tid >> 6, l = tid & 63;
  for (int i = tid; i < 1024; i += 256) ((uint4*)sW)[i] = ((const uint4*)W2T)[i];
  int bm = blockIdx.x * 128;
  f32x4 acc[2];
  acc[0] = (f32x4){0.f, 0.f, 0.f, 0.f};
  acc[1] = (f32x4){0.f, 0.f, 0.f, 0.f};
  int lr = l >> 2, lc = (l & 3) * 8;
  for (int k0 = 0; k0 < F1; k0 += 32) {
    #pragma unroll
    for (int i = 0; i < 2; ++i) {
      int ra = bm + i * 64 + w * 16 + lr;
      if (ra >= M) ra = M - 1;
      gld_lds16(A + (size_t)ra * F1 + k0 + lc, (char*)sA + i * 4096 + w * 1024);
    }
    __syncthreads();
    bf16x8 bfv = *(const bf16x8*)&sW[(l & 15) * 512 + k0 + (l >> 4) * 8];
    #pragma unroll
    for (int mi = 0; mi < 2; ++mi) {
      bf16x8 af = *(const bf16x8*)&sA[(w * 32 + mi * 16 + (l & 15)) * 32 + (l >> 4) * 8];
      acc[mi] = __builtin_amdgcn_mfma_f32_16x16x32_bf16(af, bfv, acc[mi], 0, 0, 0);
    }
    __syncthreads();
  }
  float asv = a_src2[l & 15], adv = a_dst2[l & 15];
  #pragma unroll
  for (int mi = 0; mi < 2; ++mi) {
    #pragma unroll
    for (int j = 0; j < 4; ++j) {
      int r = bm + w * 32 + mi * 16 + (l >> 4) * 4 + j;
      float val = acc[mi][j];
      float s = val * asv, d = val * adv;
      s += __shfl_xor(s, 1); s += __shfl_xor(s, 2); s += __shfl_xor(s, 4); s += __shfl_xor(s, 8);
      d += __shfl_xor(d, 1); d += __shfl_xor(d, 2); d += __shfl_xor(d, 4); d += __shfl_xor(d, 8);
      if (r < M) {
        t2[(size_t)r * OUT_CH + (l & 15)] = val;
        if ((l & 15) == 0) { as2[r] = s; ad2[r] = d; }
      }
    }
  }
}

// ---------------- aggr2: segment softmax (no max) + gather + log_softmax ----------------

__global__ __launch_bounds__(64) void aggr2_kernel(const float* __restrict__ t2,
                                                   const float* __restrict__ as2,
                                                   const float* __restrict__ ad2,
                                                   const int* __restrict__ offsets,
                                                   const int* __restrict__ csr_src,
                                                   const float* __restrict__ b2,
                                                   float* __restrict__ out, int N) {
  int node = blockIdx.x;
  int lane = threadIdx.x;  // 64
  int beg = offsets[node];
  int deg = offsets[node + 1] - beg;
  float ad = ad2[node];
  float acc = 0.f, den = 0.f;
  int eg = lane >> 4, c = lane & 15;
  for (int base = 0; base < deg; base += 4) {
    int j = base + eg;
    if (j < deg) {
      int s = csr_src[beg + j];
      float e = as2[s] + ad;
      e = (e > 0.f) ? e : NEG * e;
      float p = __expf(e);
      acc += p * t2[(size_t)s * OUT_CH + c];
      if (c == 0) den += p;
    }
  }
  acc += __shfl_xor(acc, 16); acc += __shfl_xor(acc, 32);
  den += __shfl_xor(den, 16); den += __shfl_xor(den, 32);
  den = __shfl(den, 0);
  float val = acc / (den + 1e-16f) + b2[c];
  float mx = val;
  #pragma unroll
  for (int off = 1; off < 16; off <<= 1) mx = fmaxf(mx, __shfl_xor(mx, off));
  float ex = __expf(val - mx);
  float se = ex;
  #pragma unroll
  for (int off = 1; off < 16; off <<= 1) se += __shfl_xor(se, off);
  float ls = val - mx - logf(se);
  if (lane < 16) out[(size_t)node * OUT_CH + lane] = ls;
}

// ---------------- launch ----------------

extern "C" void kernel_launch(void* const* d_in, const int* in_sizes, int n_in,
                              void* d_out, int out_size, void* d_ws, size_t ws_size,
                              hipStream_t stream) {
  const float* x      = (const float*)d_in[0];
  const int*   ei     = (const int*)d_in[1];
  const float* W1     = (const float*)d_in[2];
  const float* a_src1 = (const float*)d_in[3];
  const float* a_dst1 = (const float*)d_in[4];
  const float* b1     = (const float*)d_in[5];
  const float* W2     = (const float*)d_in[6];
  const float* a_src2 = (const float*)d_in[7];
  const float* a_dst2 = (const float*)d_in[8];
  const float* b2     = (const float*)d_in[9];
  float* out = (float*)d_out;

  int N = in_sizes[0] / IN_CH;
  int E = in_sizes[1] / 2;
  int ET = E + N;

  char* w = (char*)d_ws;
  auto alloc = [&](size_t bytes) -> void* {
    void* p = (void*)w;
    w += (bytes + 255) & ~(size_t)255;
    return p;
  };
  unsigned short* h1b   = (unsigned short*)alloc((size_t)N * F1 * 2);
  unsigned short* out1b = (unsigned short*)alloc((size_t)N * F1 * 2);
  unsigned short* xb    = (unsigned short*)alloc((size_t)N * IN_CH * 2);
  unsigned short* w1t   = (unsigned short*)alloc((size_t)F1 * IN_CH * 2);
  unsigned short* w2t   = (unsigned short*)alloc((size_t)OUT_CH * F1 * 2);
  float* as1   = (float*)alloc((size_t)N * HEADS * 4);
  float* ad1   = (float*)alloc((size_t)N * HEADS * 4);
  float* t2    = (float*)alloc((size_t)N * OUT_CH * 4);
  float* as2   = (float*)alloc((size_t)N * 4);
  float* ad2   = (float*)alloc((size_t)N * 4);
  int* counts  = (int*)alloc((size_t)N * 4);
  int* offsets = (int*)alloc((size_t)(N + 1) * 4);
  int* cursor  = (int*)alloc((size_t)N * 4);
  int* bsum    = (int*)alloc(256 * 4);
  int* bpre    = (int*)alloc(256 * 4);
  int* csr_src = (int*)alloc((size_t)ET * 4);

  int nb = (N + 1023) / 1024;

  init_kernel<<<(N * HEADS + 255) / 256, 256, 0, stream>>>(counts, cursor, as1, ad1, N);
  prep_kernel<<<(ET + 255) / 256, 256, 0, stream>>>(ei, E, N, counts, x, xb, W1, w1t, W2, w2t);
  scan1_kernel<<<nb, 1024, 0, stream>>>(counts, offsets, bsum, N);
  scan2_kernel<<<1, 64, 0, stream>>>(bsum, bpre, nb, offsets, N);
  scan3_kernel<<<nb, 1024, 0, stream>>>(offsets, bpre, N);
  fill_kernel<<<(ET + 255) / 256, 256, 0, stream>>>(ei, E, N, offsets, cursor, csr_src);

  int gx = ((N + 127) / 128) * 4;
  gemm1_mfma<<<gx, 256, 0, stream>>>(xb, w1t, a_src1, a_dst1, h1b, as1, ad1, N);
  aggr1_kernel<<<(N + 3) / 4, 256, 0, stream>>>((const uint4*)h1b, as1, ad1, offsets, csr_src,
                                                b1, (uint4*)out1b, N);
  gemm2_mfma<<<(N + 127) / 128, 256, 0, stream>>>(out1b, w2t, a_src2, a_dst2, t2, as2, ad2, N);
  aggr2_kernel<<<N, 64, 0, stream>>>(t2, as2, ad2, offsets, csr_src, b2, out, N);
}